// Round 9
// baseline (709.383 us; speedup 1.0000x reference)
//
#include <hip/hip_runtime.h>
#include <hip/hip_bf16.h>

#define T 512
#define H 128
#define V 32000
#define B 2
#define CH 64   // RNN steps staged per LDS chunk

typedef __attribute__((ext_vector_type(8))) short bf16x8;
typedef __attribute__((ext_vector_type(4))) float f32x4;

__device__ __forceinline__ unsigned short f2bf(float f){
  unsigned int u = __float_as_uint(f);
  u = (u + 0x7FFFu + ((u >> 16) & 1u)) >> 16;
  return (unsigned short)u;
}

// tanh(x) = 1 - 2/(e^{2x}+1). e->inf gives 1, e->0 gives -1 (no clamp needed).
__device__ __forceinline__ float fast_tanh(float x){
  float e = __expf(2.f * x);
  return 1.f - __fdividef(2.f, e + 1.f);
}

// async global->LDS, 16B per lane; lds base must be wave-uniform.
__device__ __forceinline__ void gload_lds16(const float* g, float* l){
  __builtin_amdgcn_global_load_lds((const __attribute__((address_space(1))) void*)g,
                                   (__attribute__((address_space(3))) void*)l, 16, 0, 0);
}

// ---------------- Kernel 1: prep = embedding + input-projection (xp only) ----------------
// (Wfc->bf16 conversion moved into rnn_kernel's extra blocks: it is independent work
// that now runs on the 254 idle CUs DURING the serial scan instead of serially before.)
__global__ __launch_bounds__(128) void prep_kernel(const int* __restrict__ x,
    const float* __restrict__ table, const float* __restrict__ W_ih,
    const float* __restrict__ b_ih, const float* __restrict__ b_hh,
    float* __restrict__ xp){
  int blk = blockIdx.x;
  int tid = threadIdx.x;
  __shared__ __align__(16) float e[32];
  if (tid < 32) e[tid] = table[(size_t)x[blk] * 32 + tid];
  __syncthreads();
  const float* wr = W_ih + tid * 32;
  float a0 = 0.f, a1 = 0.f, a2 = 0.f, a3 = 0.f;
  #pragma unroll
  for (int k = 0; k < 32; k += 4){
    float4 w4 = *(const float4*)(wr + k);
    float4 e4 = *(const float4*)(e + k);
    a0 += w4.x * e4.x; a1 += w4.y * e4.y; a2 += w4.z * e4.z; a3 += w4.w * e4.w;
  }
  xp[(size_t)blk * H + tid] = (a0 + a1) + (a2 + a3) + b_ih[tid] + b_hh[tid];
}

// ---------------- Kernel 2: serial RNN scan — ONE WAVE per batch chain ----------------
// (Ledger r2-r7: conflicts -262K cyc -> -4us; DPP -> 0; DS-halving+narrower barrier
// -> -27us; residual ~920 cyc/step = serial latency chain + multi-wave resync.)
// 64 lanes, lane l owns rows {2l, 2l+1} with FULL k in 256 pinned VGPRs.
//  - h fragment reads are same-address broadcasts: conflict-free, no swizzle.
//  - NO cross-lane reduction (dot is lane-local) — DPP/shfl gone from the chain.
//  - 1-wave block: __syncthreads has no multi-wave resync; waitcnt-only.
// Deliberate cost: FMA issue 256 instr x 2cyc = 512 cyc/step on one SIMD = the new
// known floor. Steady-state loop still has ZERO global memory ops.
// Blocks >= B convert Wfc->bf16 (independent; hidden under the scan).
__global__ __launch_bounds__(64, 1) void rnn_kernel(const float* __restrict__ xp,
    const float* __restrict__ hidden, const float* __restrict__ W_hh,
    const float* __restrict__ Wfc, float* __restrict__ rnn,
    float* __restrict__ hid_out, unsigned short* __restrict__ wfcb){
  if (blockIdx.x >= B){
    size_t base = (size_t)(blockIdx.x - B) * 1024 + (size_t)threadIdx.x * 16;
    #pragma unroll
    for (int j = 0; j < 4; ++j){
      float4 f = *(const float4*)(Wfc + base + j * 4);
      ushort4 o; o.x = f2bf(f.x); o.y = f2bf(f.y); o.z = f2bf(f.z); o.w = f2bf(f.w);
      *(ushort4*)(wfcb + base + j * 4) = o;
    }
    return;
  }
  int b = blockIdx.x;
  int l = threadIdx.x;
  int r0 = 2 * l;
  const float* wr = W_hh + (size_t)r0 * H;
  // rows r0 (A*) and r0+1 (B*): 64 f32x4 = 256 VGPRs, pinned via asm (RA cannot
  // rematerialize an asm result -> no per-step reloads).
#define DECLW(n) f32x4 A##n = *(const f32x4*)(wr + 4 * n); \
                 f32x4 B##n = *(const f32x4*)(wr + H + 4 * n);
  DECLW(0)  DECLW(1)  DECLW(2)  DECLW(3)  DECLW(4)  DECLW(5)  DECLW(6)  DECLW(7)
  DECLW(8)  DECLW(9)  DECLW(10) DECLW(11) DECLW(12) DECLW(13) DECLW(14) DECLW(15)
  DECLW(16) DECLW(17) DECLW(18) DECLW(19) DECLW(20) DECLW(21) DECLW(22) DECLW(23)
  DECLW(24) DECLW(25) DECLW(26) DECLW(27) DECLW(28) DECLW(29) DECLW(30) DECLW(31)
#undef DECLW
  asm volatile("" : "+v"(A0), "+v"(A1), "+v"(A2),  "+v"(A3),
                    "+v"(A4), "+v"(A5), "+v"(A6),  "+v"(A7),
                    "+v"(B0), "+v"(B1), "+v"(B2),  "+v"(B3),
                    "+v"(B4), "+v"(B5), "+v"(B6),  "+v"(B7));
  asm volatile("" : "+v"(A8), "+v"(A9), "+v"(A10), "+v"(A11),
                    "+v"(A12),"+v"(A13),"+v"(A14), "+v"(A15),
                    "+v"(B8), "+v"(B9), "+v"(B10), "+v"(B11),
                    "+v"(B12),"+v"(B13),"+v"(B14), "+v"(B15));
  asm volatile("" : "+v"(A16),"+v"(A17),"+v"(A18), "+v"(A19),
                    "+v"(A20),"+v"(A21),"+v"(A22), "+v"(A23),
                    "+v"(B16),"+v"(B17),"+v"(B18), "+v"(B19),
                    "+v"(B20),"+v"(B21),"+v"(B22), "+v"(B23));
  asm volatile("" : "+v"(A24),"+v"(A25),"+v"(A26), "+v"(A27),
                    "+v"(A28),"+v"(A29),"+v"(A30), "+v"(A31),
                    "+v"(B24),"+v"(B25),"+v"(B26), "+v"(B27),
                    "+v"(B28),"+v"(B29),"+v"(B30), "+v"(B31));

  __shared__ __align__(16) float xs[2][CH][H];   // 64 KB: xp chunk double-buffer
  __shared__ __align__(16) float hist[CH][H];    // 32 KB: h history
  __shared__ __align__(16) float hb[2][H];       // ping-pong h state (linear)

  const float* xpb = xp + (size_t)b * T * H;

  // prologue: async-load chunk 0 (32 issues x 64 lanes x 16B = 32 KB)
  #pragma unroll
  for (int is = 0; is < 32; ++is)
    gload_lds16(xpb + is * 256 + l * 4, &xs[0][0][0] + is * 256);
  *(float2*)(&hb[0][r0]) = *(const float2*)(&hidden[b * H + r0]);
  __syncthreads();   // drains chunk-0 load (waitcnt only; 1 wave)

  float hn0 = 0.f, hn1 = 0.f;
  int cur = 0, buf = 0;
  for (int chunk = 0; chunk < T / CH; ++chunk){
    // issue next chunk's loads; they drain at this chunk's first step barrier
    // (one latency hit amortized over CH steps).
    if (chunk + 1 < T / CH){
      const float* src = xpb + (size_t)(chunk + 1) * CH * H;
      #pragma unroll
      for (int is = 0; is < 32; ++is)
        gload_lds16(src + is * 256 + l * 4, &xs[buf ^ 1][0][0] + is * 256);
    }
    #pragma unroll 1
    for (int s = 0; s < CH; ++s){
      float2 xv = *(const float2*)(&xs[buf][s][r0]);  // 2-way aliasing (free)
      const float* hbc = &hb[cur][0];                 // same addr all lanes: broadcast
      float a0 = 0.f, a1 = 0.f, a2 = 0.f, a3 = 0.f;
      float b0 = 0.f, b1 = 0.f, b2 = 0.f, b3 = 0.f;
#define FMA8(n) { f32x4 hv = *(const f32x4*)(hbc + 4 * n); \
    a0 = fmaf(hv.x, A##n.x, a0); a1 = fmaf(hv.y, A##n.y, a1); \
    a2 = fmaf(hv.z, A##n.z, a2); a3 = fmaf(hv.w, A##n.w, a3); \
    b0 = fmaf(hv.x, B##n.x, b0); b1 = fmaf(hv.y, B##n.y, b1); \
    b2 = fmaf(hv.z, B##n.z, b2); b3 = fmaf(hv.w, B##n.w, b3); }
      FMA8(0)  FMA8(1)  FMA8(2)  FMA8(3)  FMA8(4)  FMA8(5)  FMA8(6)  FMA8(7)
      FMA8(8)  FMA8(9)  FMA8(10) FMA8(11) FMA8(12) FMA8(13) FMA8(14) FMA8(15)
      FMA8(16) FMA8(17) FMA8(18) FMA8(19) FMA8(20) FMA8(21) FMA8(22) FMA8(23)
      FMA8(24) FMA8(25) FMA8(26) FMA8(27) FMA8(28) FMA8(29) FMA8(30) FMA8(31)
#undef FMA8
      hn0 = fast_tanh(xv.x + (a0 + a1) + (a2 + a3));
      hn1 = fast_tanh(xv.y + (b0 + b1) + (b2 + b3));
      float2 hw; hw.x = hn0; hw.y = hn1;
      *(float2*)(&hb[cur ^ 1][r0]) = hw;   // next-step state (critical)
      *(float2*)(&hist[s][r0]) = hw;       // history
      __syncthreads();                     // 1 wave: waitcnt-only, no resync
      cur ^= 1;
    }
    // flush h history: 32 rounds x 64 threads x float4 = 32 KB coalesced
    {
      const float* hsrc = &hist[0][0];
      float* dst = rnn + (size_t)b * T * H + (size_t)chunk * CH * H;
      #pragma unroll
      for (int r = 0; r < 32; ++r)
        *(float4*)(dst + r * 256 + l * 4) = *(const float4*)(hsrc + r * 256 + l * 4);
    }
    buf ^= 1;
    __syncthreads();   // flush reads complete before hist reuse next chunk
  }
  float2 hw; hw.x = hn0; hw.y = hn1;
  *(float2*)(&hid_out[b * H + r0]) = hw;
}

// ---------------- Kernel 3: query/key projections ----------------
__global__ __launch_bounds__(256) void qk_kernel(const float* __restrict__ rnn,
    const float* __restrict__ W1, const float* __restrict__ W2,
    float* __restrict__ q, float* __restrict__ ky){
  int bt = blockIdx.x;
  int tid = threadIdx.x;
  __shared__ __align__(16) float r[H];
  if (tid < H) r[tid] = rnn[(size_t)bt * H + tid];
  __syncthreads();
  int i = tid & (H - 1);
  const float* wrow = ((tid < H) ? W1 : W2) + (size_t)i * H;
  float a0 = 0.f, a1 = 0.f, a2 = 0.f, a3 = 0.f;
  #pragma unroll 8
  for (int k = 0; k < H; k += 4){
    float4 w4 = *(const float4*)(wrow + k);
    float4 r4 = *(const float4*)(r + k);
    a0 += w4.x * r4.x; a1 += w4.y * r4.y; a2 += w4.z * r4.z; a3 += w4.w * r4.w;
  }
  float res = (a0 + a1) + (a2 + a3);
  if (tid < H) q[(size_t)bt * H + i] = res;
  else         ky[(size_t)bt * H + i] = res;
}

// ---------------- Kernel 4: attention scores + softmax + context + Wp/relu ----------------
__global__ __launch_bounds__(256) void attn_kernel(const float* __restrict__ rnn,
    const float* __restrict__ q, const float* __restrict__ ky,
    const float* __restrict__ v, const float* __restrict__ Wp,
    const float* __restrict__ bp, float* __restrict__ wout,
    unsigned short* __restrict__ outb){
  int bt = blockIdx.x;
  int b = bt >> 9, t = bt & (T - 1);
  int tid = threadIdx.x;
  __shared__ __align__(16) float qL[H], vL[H], rrL[H], ctxL[H];
  __shared__ __align__(16) float ctx2[2][H];
  __shared__ __align__(16) float scL[T], wL[T];
  __shared__ float red[4], red2[4];
  if (tid < H){
    qL[tid]  = q[(size_t)bt * H + tid];
    vL[tid]  = v[tid];
    rrL[tid] = rnn[(size_t)bt * H + tid];
  }
  __syncthreads();
  for (int s = tid; s < T; s += 256){
    float sc = -1e30f;
    if (s <= t){
      const float* kr = ky + (size_t)(b * T + s) * H;
      float a0 = 0.f, a1 = 0.f, a2 = 0.f, a3 = 0.f;
      #pragma unroll 4
      for (int h = 0; h < H; h += 4){
        float4 kv = *(const float4*)(kr + h);
        float4 qv = *(const float4*)(qL + h);
        float4 vv = *(const float4*)(vL + h);
        a0 += fast_tanh(qv.x + kv.x) * vv.x;
        a1 += fast_tanh(qv.y + kv.y) * vv.y;
        a2 += fast_tanh(qv.z + kv.z) * vv.z;
        a3 += fast_tanh(qv.w + kv.w) * vv.w;
      }
      sc = (a0 + a1) + (a2 + a3);
    }
    scL[s] = sc;
  }
  __syncthreads();
  float m = -1e30f;
  for (int s = tid; s < T; s += 256) m = fmaxf(m, scL[s]);
  #pragma unroll
  for (int o = 32; o > 0; o >>= 1) m = fmaxf(m, __shfl_xor(m, o));
  if ((tid & 63) == 0) red[tid >> 6] = m;
  __syncthreads();
  float mx = fmaxf(fmaxf(red[0], red[1]), fmaxf(red[2], red[3]));
  float ls = 0.f;
  for (int s = tid; s < T; s += 256){
    float e = (s <= t) ? __expf(scL[s] - mx) : 0.f;
    wL[s] = e; ls += e;
  }
  #pragma unroll
  for (int o = 32; o > 0; o >>= 1) ls += __shfl_xor(ls, o);
  if ((tid & 63) == 0) red2[tid >> 6] = ls;
  __syncthreads();
  float inv = 1.f / (red2[0] + red2[1] + red2[2] + red2[3]);
  for (int s = tid; s < T; s += 256){
    float wv = wL[s] * inv;
    wL[s] = wv;
    wout[(size_t)bt * T + s] = wv;
  }
  __syncthreads();
  // context: all 256 threads. thread -> dim i2 = tid&127, s-parity hf = tid>>7.
  {
    int i2 = tid & (H - 1), hf = tid >> 7;
    const float* rb = rnn + (size_t)b * T * H + i2;
    float c0 = 0.f, c1 = 0.f, c2 = 0.f, c3 = 0.f;
    int s = hf;
    for (; s + 6 <= t; s += 8){
      c0 += wL[s]     * rb[(size_t)s * H];
      c1 += wL[s + 2] * rb[(size_t)(s + 2) * H];
      c2 += wL[s + 4] * rb[(size_t)(s + 4) * H];
      c3 += wL[s + 6] * rb[(size_t)(s + 6) * H];
    }
    for (; s <= t; s += 2) c0 += wL[s] * rb[(size_t)s * H];
    ctx2[hf][i2] = (c0 + c1) + (c2 + c3);
  }
  __syncthreads();
  if (tid < H) ctxL[tid] = ctx2[0][tid] + ctx2[1][tid];
  __syncthreads();
  if (tid < H){
    const float* wp = Wp + (size_t)tid * (2 * H);
    float a0 = 0.f, a1 = 0.f, a2 = 0.f, a3 = 0.f;
    #pragma unroll 8
    for (int k = 0; k < H; k += 4){
      float4 w4 = *(const float4*)(wp + k);
      float4 r4 = *(const float4*)(rrL + k);
      a0 += w4.x * r4.x; a1 += w4.y * r4.y; a2 += w4.z * r4.z; a3 += w4.w * r4.w;
    }
    #pragma unroll 8
    for (int k = 0; k < H; k += 4){
      float4 w4 = *(const float4*)(wp + H + k);
      float4 c4 = *(const float4*)(ctxL + k);
      a0 += w4.x * c4.x; a1 += w4.y * c4.y; a2 += w4.z * c4.z; a3 += w4.w * c4.w;
    }
    float o = bp[tid] + (a0 + a1) + (a2 + a3);
    o = fmaxf(o, 0.f);
    outb[(size_t)bt * H + tid] = f2bf(o);
  }
}

// ---------------- Kernel 5: logits = out @ Wfc.T + bfc  (bf16 MFMA) ----------------
__global__ __launch_bounds__(256, 1) void gemm_kernel(const unsigned short* __restrict__ Ab,
    const unsigned short* __restrict__ Bb, const float* __restrict__ bfc,
    float* __restrict__ Cout){
  int tid = threadIdx.x;
  int l = tid & 63, wv = tid >> 6;
  int lm = l & 15, lq = l >> 4;
  int nBase = blockIdx.x * 128;
  bf16x8 bw[32];
  const unsigned short* bp = Bb + (size_t)(nBase + lm) * H + lq * 8;
  #pragma unroll
  for (int sub = 0; sub < 8; ++sub)
    #pragma unroll
    for (int kk = 0; kk < 4; ++kk)
      bw[sub * 4 + kk] = *(const bf16x8*)(bp + (size_t)sub * 16 * H + kk * 32);
  float bias[8];
  #pragma unroll
  for (int sub = 0; sub < 8; ++sub) bias[sub] = bfc[nBase + lm + sub * 16];
  #pragma unroll 1
  for (int mb = 0; mb < 16; ++mb){
    int rowA = mb * 64 + wv * 16 + lm;
    const unsigned short* ap = Ab + (size_t)rowA * H + lq * 8;
    bf16x8 af[4];
    #pragma unroll
    for (int kk = 0; kk < 4; ++kk) af[kk] = *(const bf16x8*)(ap + kk * 32);
    f32x4 acc[8];
    #pragma unroll
    for (int s = 0; s < 8; ++s) acc[s] = (f32x4){0.f, 0.f, 0.f, 0.f};
    #pragma unroll
    for (int kk = 0; kk < 4; ++kk)
      #pragma unroll
      for (int sub = 0; sub < 8; ++sub)
        acc[sub] = __builtin_amdgcn_mfma_f32_16x16x32_bf16(af[kk], bw[sub * 4 + kk], acc[sub], 0, 0, 0);
    int row0 = mb * 64 + wv * 16 + lq * 4;
    #pragma unroll
    for (int sub = 0; sub < 8; ++sub){
      int c = nBase + lm + sub * 16;
      #pragma unroll
      for (int r = 0; r < 4; ++r)
        Cout[(size_t)(row0 + r) * V + c] = acc[sub][r] + bias[sub];
    }
  }
}

extern "C" void kernel_launch(void* const* d_in, const int* in_sizes, int n_in,
                              void* d_out, int out_size, void* d_ws, size_t ws_size,
                              hipStream_t stream){
  const int*   x      = (const int*)d_in[0];
  const float* hidden = (const float*)d_in[1];
  const float* table  = (const float*)d_in[2];
  const float* W_ih   = (const float*)d_in[3];
  const float* W_hh   = (const float*)d_in[4];
  const float* b_ih   = (const float*)d_in[5];
  const float* b_hh   = (const float*)d_in[6];
  const float* W1     = (const float*)d_in[7];
  const float* W2     = (const float*)d_in[8];
  const float* v      = (const float*)d_in[9];
  const float* Wp     = (const float*)d_in[10];
  const float* bp     = (const float*)d_in[11];
  const float* Wfc    = (const float*)d_in[12];
  const float* bfc    = (const float*)d_in[13];

  float* out     = (float*)d_out;
  float* logits  = out;                              // (B,T,V)
  float* hid_out = out + (size_t)B * T * V;          // (1,B,H)
  float* w_out   = hid_out + (size_t)B * H;          // (B,T,T)

  float* xp  = (float*)d_ws;
  float* rnn = xp  + (size_t)B * T * H;
  float* q   = rnn + (size_t)B * T * H;
  float* ky  = q   + (size_t)B * T * H;
  unsigned short* outb = (unsigned short*)(ky + (size_t)B * T * H);
  unsigned short* wfcb = outb + (size_t)B * T * H;

  prep_kernel<<<B * T, 128, 0, stream>>>(x, table, W_ih, b_ih, b_hh, xp);
  rnn_kernel<<<B + (V * H) / 1024, 64, 0, stream>>>(xp, hidden, W_hh, Wfc, rnn, hid_out, wfcb);
  qk_kernel<<<B * T, 256, 0, stream>>>(rnn, W1, W2, q, ky);
  attn_kernel<<<B * T, 256, 0, stream>>>(rnn, q, ky, v, Wp, bp, w_out, outb);
  gemm_kernel<<<V / 128, 256, 0, stream>>>(outb, wfcb, bfc, logits);
}

// Round 10
// 444.837 us; speedup vs baseline: 1.5947x; 1.5947x over previous
//
#include <hip/hip_runtime.h>
#include <hip/hip_bf16.h>

#define T 512
#define H 128
#define V 32000
#define B 2
#define CH 64   // RNN steps staged per LDS chunk

typedef __attribute__((ext_vector_type(8))) short bf16x8;
typedef __attribute__((ext_vector_type(4))) float f32x4;

__device__ __forceinline__ unsigned short f2bf(float f){
  unsigned int u = __float_as_uint(f);
  u = (u + 0x7FFFu + ((u >> 16) & 1u)) >> 16;
  return (unsigned short)u;
}

// tanh(x) = 1 - 2/(e^{2x}+1). e->inf gives 1, e->0 gives -1 (no clamp needed).
__device__ __forceinline__ float fast_tanh(float x){
  float e = __expf(2.f * x);
  return 1.f - __fdividef(2.f, e + 1.f);
}

// Quad (4-lane) sum via DPP quad_perm — VALU-only, frees the LDS pipe.
__device__ __forceinline__ float quad_reduce_add(float x){
  int y1 = __builtin_amdgcn_mov_dpp(__float_as_int(x), 0xB1, 0xF, 0xF, true);
  float s1 = x + __int_as_float(y1);
  int y2 = __builtin_amdgcn_mov_dpp(__float_as_int(s1), 0x4E, 0xF, 0xF, true);
  return s1 + __int_as_float(y2);
}

// h-vector bank swizzle: h[k] (k = q*32 + 4n + j) lives at LDS word n*16 + q*4 + j.
// Per ds_read_b128 the 4 distinct q-addresses cover 16 consecutive banks ->
// conflict-free (verified r5: 262K -> 6K SQ_LDS_BANK_CONFLICT).
__device__ __forceinline__ int hswz(int k){
  return ((k >> 2) & 7) * 16 + ((k >> 5) << 2) + (k & 3);
}

// async global->LDS, 16B per lane; lds base must be wave-uniform.
__device__ __forceinline__ void gload_lds16(const float* g, float* l){
  __builtin_amdgcn_global_load_lds((const __attribute__((address_space(1))) void*)g,
                                   (__attribute__((address_space(3))) void*)l, 16, 0, 0);
}

// ---------------- Kernel 1: prep = embedding + input-projection (xp only) ----------------
__global__ __launch_bounds__(128) void prep_kernel(const int* __restrict__ x,
    const float* __restrict__ table, const float* __restrict__ W_ih,
    const float* __restrict__ b_ih, const float* __restrict__ b_hh,
    float* __restrict__ xp){
  int blk = blockIdx.x;
  int tid = threadIdx.x;
  __shared__ __align__(16) float e[32];
  if (tid < 32) e[tid] = table[(size_t)x[blk] * 32 + tid];
  __syncthreads();
  const float* wr = W_ih + tid * 32;
  float a0 = 0.f, a1 = 0.f, a2 = 0.f, a3 = 0.f;
  #pragma unroll
  for (int k = 0; k < 32; k += 4){
    float4 w4 = *(const float4*)(wr + k);
    float4 e4 = *(const float4*)(e + k);
    a0 += w4.x * e4.x; a1 += w4.y * e4.y; a2 += w4.z * e4.z; a3 += w4.w * e4.w;
  }
  xp[(size_t)blk * H + tid] = (a0 + a1) + (a2 + a3) + b_ih[tid] + b_hh[tid];
}

// ---------------- Kernel 2: serial RNN scan (r7 config, MEASURED BEST: 197us) ----------
// r3 (1 wave/SIMD, linear hb) = 285us; r7 (4 waves, hswz, 2 rows/lane) = 197us;
// r9 (1 wave total) = 467us — one wave cannot hide its own ds_read latency. The
// r7 shape is the measured optimum for this exchange structure; FROZEN.
// 256 threads: lane -> rows {2qp, 2qp+1} (qp=tid>>2), k-slice q=tid&3; 128 weight
// VGPRs pinned via asm. Steady-state loop has ZERO global memory ops.
// Blocks >= B convert Wfc->bf16 (independent work, hidden under the scan on the
// 254 idle CUs — the one sound idea from r9, kept).
__global__ __launch_bounds__(256, 1) void rnn_kernel(const float* __restrict__ xp,
    const float* __restrict__ hidden, const float* __restrict__ W_hh,
    const float* __restrict__ Wfc, float* __restrict__ rnn,
    float* __restrict__ hid_out, unsigned short* __restrict__ wfcb){
  if (blockIdx.x >= B){
    size_t base = (size_t)(blockIdx.x - B) * 4096;
    #pragma unroll
    for (int j = 0; j < 4; ++j){
      size_t off = base + (size_t)j * 1024 + (size_t)threadIdx.x * 4;
      float4 f = *(const float4*)(Wfc + off);
      ushort4 o; o.x = f2bf(f.x); o.y = f2bf(f.y); o.z = f2bf(f.z); o.w = f2bf(f.w);
      *(ushort4*)(wfcb + off) = o;
    }
    return;
  }
  int b = blockIdx.x;
  int tid = threadIdx.x;
  int qp = tid >> 2, q = tid & 3;
  int wv = tid >> 6;                 // wave id (uniform within wave)
  int r0 = 2 * qp;
  const float* wra = W_hh + (size_t)r0 * H + q * 32;   // row r0, slice q
  const float* wrb = wra + H;                          // row r0+1, slice q
  f32x4 A0 = *(const f32x4*)(wra);
  f32x4 A1 = *(const f32x4*)(wra + 4);
  f32x4 A2 = *(const f32x4*)(wra + 8);
  f32x4 A3 = *(const f32x4*)(wra + 12);
  f32x4 A4 = *(const f32x4*)(wra + 16);
  f32x4 A5 = *(const f32x4*)(wra + 20);
  f32x4 A6 = *(const f32x4*)(wra + 24);
  f32x4 A7 = *(const f32x4*)(wra + 28);
  f32x4 B0 = *(const f32x4*)(wrb);
  f32x4 B1 = *(const f32x4*)(wrb + 4);
  f32x4 B2 = *(const f32x4*)(wrb + 8);
  f32x4 B3 = *(const f32x4*)(wrb + 12);
  f32x4 B4 = *(const f32x4*)(wrb + 16);
  f32x4 B5 = *(const f32x4*)(wrb + 20);
  f32x4 B6 = *(const f32x4*)(wrb + 24);
  f32x4 B7 = *(const f32x4*)(wrb + 28);
  // pin weights in registers (RA cannot rematerialize an asm result)
  asm volatile("" : "+v"(A0), "+v"(A1), "+v"(A2), "+v"(A3),
                    "+v"(A4), "+v"(A5), "+v"(A6), "+v"(A7));
  asm volatile("" : "+v"(B0), "+v"(B1), "+v"(B2), "+v"(B3),
                    "+v"(B4), "+v"(B5), "+v"(B6), "+v"(B7));

  __shared__ __align__(16) float xs[2][CH][H];   // 64 KB: xp chunk double-buffer
  __shared__ __align__(16) float hist[CH][H];    // 32 KB: h history (linear layout)
  __shared__ __align__(16) float hb[2][H];       // ping-pong h state (hswz layout)

  const float* xpb = xp + (size_t)b * T * H;

  // prologue: async-load chunk 0 (8 issue rounds x 256 lanes x 16B = 32 KB)
  #pragma unroll
  for (int is = 0; is < 8; ++is)
    gload_lds16(xpb + is * 1024 + tid * 4, &xs[0][0][0] + is * 1024 + wv * 256);
  if (tid < H) hb[0][hswz(tid)] = hidden[b * H + tid];
  __syncthreads();   // drains chunk-0 load + hidden load

  // swizzled write position: rows r0,r0+1 land on adjacent words (r0&3 in {0,2})
  int wpos = hswz(r0);
  float hn0 = 0.f, hn1 = 0.f;
  int cur = 0, buf = 0;
  for (int chunk = 0; chunk < T / CH; ++chunk){
    // issue next chunk's loads now; they drain at this chunk's FIRST inner barrier
    if (chunk + 1 < T / CH){
      const float* src = xpb + (size_t)(chunk + 1) * CH * H;
      #pragma unroll
      for (int is = 0; is < 8; ++is)
        gload_lds16(src + is * 1024 + tid * 4, &xs[buf ^ 1][0][0] + is * 1024 + wv * 256);
    }
    for (int s = 0; s < CH; ++s){
      float2 xv = *(const float2*)(&xs[buf][s][r0]);  // ds_read_b64 (4-lane bcast)
      const float* hs = &hb[cur][q * 4];              // swizzled base; block n at +16n
      float a0 = 0.f, a1 = 0.f, b0 = 0.f, b1 = 0.f;
#define FMA8(n) { f32x4 hv = *(const f32x4*)(hs + 16 * n); \
    a0 = fmaf(hv.x, A##n.x, a0); a1 = fmaf(hv.y, A##n.y, a1); \
    a0 = fmaf(hv.z, A##n.z, a0); a1 = fmaf(hv.w, A##n.w, a1); \
    b0 = fmaf(hv.x, B##n.x, b0); b1 = fmaf(hv.y, B##n.y, b1); \
    b0 = fmaf(hv.z, B##n.z, b0); b1 = fmaf(hv.w, B##n.w, b1); }
      FMA8(0) FMA8(1) FMA8(2) FMA8(3) FMA8(4) FMA8(5) FMA8(6) FMA8(7)
#undef FMA8
      float sa = quad_reduce_add(a0 + a1);
      float sb = quad_reduce_add(b0 + b1);
      hn0 = fast_tanh(xv.x + sa);
      hn1 = fast_tanh(xv.y + sb);
      if (q == 0){                       // next-step state (swizzled, adjacent words)
        float2 hw; hw.x = hn0; hw.y = hn1;
        *(float2*)(&hb[cur ^ 1][wpos]) = hw;
      }
      if (q == 1){                       // history (linear) — parallel lane
        float2 hw; hw.x = hn0; hw.y = hn1;
        *(float2*)(&hist[s][r0]) = hw;
      }
      __syncthreads();                   // steady state: lgkm-only drain (no vmem)
      cur ^= 1;
    }
    // flush h history: 8 rounds, each 256 threads x float4 = 4 KB contiguous
    {
      const float* hsrc = &hist[0][0];
      float* dst = rnn + (size_t)b * T * H + (size_t)chunk * CH * H;
      #pragma unroll
      for (int r = 0; r < 8; ++r)
        *(float4*)(dst + r * 1024 + tid * 4) = *(const float4*)(hsrc + r * 1024 + tid * 4);
    }
    buf ^= 1;
    __syncthreads();   // flush LDS reads complete before hist reuse next chunk
  }
  if (q == 0){
    float2 hw; hw.x = hn0; hw.y = hn1;
    *(float2*)(&hid_out[b * H + r0]) = hw;
  }
}

// ---------------- Kernel 3: query/key projections ----------------
__global__ __launch_bounds__(256) void qk_kernel(const float* __restrict__ rnn,
    const float* __restrict__ W1, const float* __restrict__ W2,
    float* __restrict__ q, float* __restrict__ ky){
  int bt = blockIdx.x;
  int tid = threadIdx.x;
  __shared__ __align__(16) float r[H];
  if (tid < H) r[tid] = rnn[(size_t)bt * H + tid];
  __syncthreads();
  int i = tid & (H - 1);
  const float* wrow = ((tid < H) ? W1 : W2) + (size_t)i * H;
  float a0 = 0.f, a1 = 0.f, a2 = 0.f, a3 = 0.f;
  #pragma unroll 8
  for (int k = 0; k < H; k += 4){
    float4 w4 = *(const float4*)(wrow + k);
    float4 r4 = *(const float4*)(r + k);
    a0 += w4.x * r4.x; a1 += w4.y * r4.y; a2 += w4.z * r4.z; a3 += w4.w * r4.w;
  }
  float res = (a0 + a1) + (a2 + a3);
  if (tid < H) q[(size_t)bt * H + i] = res;
  else         ky[(size_t)bt * H + i] = res;
}

// ---------------- Kernel 4: attention scores + softmax + context + Wp/relu ----------------
__global__ __launch_bounds__(256) void attn_kernel(const float* __restrict__ rnn,
    const float* __restrict__ q, const float* __restrict__ ky,
    const float* __restrict__ v, const float* __restrict__ Wp,
    const float* __restrict__ bp, float* __restrict__ wout,
    unsigned short* __restrict__ outb){
  int bt = blockIdx.x;
  int b = bt >> 9, t = bt & (T - 1);
  int tid = threadIdx.x;
  __shared__ __align__(16) float qL[H], vL[H], rrL[H], ctxL[H];
  __shared__ __align__(16) float ctx2[2][H];
  __shared__ __align__(16) float scL[T], wL[T];
  __shared__ float red[4], red2[4];
  if (tid < H){
    qL[tid]  = q[(size_t)bt * H + tid];
    vL[tid]  = v[tid];
    rrL[tid] = rnn[(size_t)bt * H + tid];
  }
  __syncthreads();
  for (int s = tid; s < T; s += 256){
    float sc = -1e30f;
    if (s <= t){
      const float* kr = ky + (size_t)(b * T + s) * H;
      float a0 = 0.f, a1 = 0.f, a2 = 0.f, a3 = 0.f;
      #pragma unroll 4
      for (int h = 0; h < H; h += 4){
        float4 kv = *(const float4*)(kr + h);
        float4 qv = *(const float4*)(qL + h);
        float4 vv = *(const float4*)(vL + h);
        a0 += fast_tanh(qv.x + kv.x) * vv.x;
        a1 += fast_tanh(qv.y + kv.y) * vv.y;
        a2 += fast_tanh(qv.z + kv.z) * vv.z;
        a3 += fast_tanh(qv.w + kv.w) * vv.w;
      }
      sc = (a0 + a1) + (a2 + a3);
    }
    scL[s] = sc;
  }
  __syncthreads();
  float m = -1e30f;
  for (int s = tid; s < T; s += 256) m = fmaxf(m, scL[s]);
  #pragma unroll
  for (int o = 32; o > 0; o >>= 1) m = fmaxf(m, __shfl_xor(m, o));
  if ((tid & 63) == 0) red[tid >> 6] = m;
  __syncthreads();
  float mx = fmaxf(fmaxf(red[0], red[1]), fmaxf(red[2], red[3]));
  float ls = 0.f;
  for (int s = tid; s < T; s += 256){
    float e = (s <= t) ? __expf(scL[s] - mx) : 0.f;
    wL[s] = e; ls += e;
  }
  #pragma unroll
  for (int o = 32; o > 0; o >>= 1) ls += __shfl_xor(ls, o);
  if ((tid & 63) == 0) red2[tid >> 6] = ls;
  __syncthreads();
  float inv = 1.f / (red2[0] + red2[1] + red2[2] + red2[3]);
  for (int s = tid; s < T; s += 256){
    float wv = wL[s] * inv;
    wL[s] = wv;
    wout[(size_t)bt * T + s] = wv;
  }
  __syncthreads();
  // context: all 256 threads. thread -> dim i2 = tid&127, s-parity hf = tid>>7.
  {
    int i2 = tid & (H - 1), hf = tid >> 7;
    const float* rb = rnn + (size_t)b * T * H + i2;
    float c0 = 0.f, c1 = 0.f, c2 = 0.f, c3 = 0.f;
    int s = hf;
    for (; s + 6 <= t; s += 8){
      c0 += wL[s]     * rb[(size_t)s * H];
      c1 += wL[s + 2] * rb[(size_t)(s + 2) * H];
      c2 += wL[s + 4] * rb[(size_t)(s + 4) * H];
      c3 += wL[s + 6] * rb[(size_t)(s + 6) * H];
    }
    for (; s <= t; s += 2) c0 += wL[s] * rb[(size_t)s * H];
    ctx2[hf][i2] = (c0 + c1) + (c2 + c3);
  }
  __syncthreads();
  if (tid < H) ctxL[tid] = ctx2[0][tid] + ctx2[1][tid];
  __syncthreads();
  if (tid < H){
    const float* wp = Wp + (size_t)tid * (2 * H);
    float a0 = 0.f, a1 = 0.f, a2 = 0.f, a3 = 0.f;
    #pragma unroll 8
    for (int k = 0; k < H; k += 4){
      float4 w4 = *(const float4*)(wp + k);
      float4 r4 = *(const float4*)(rrL + k);
      a0 += w4.x * r4.x; a1 += w4.y * r4.y; a2 += w4.z * r4.z; a3 += w4.w * r4.w;
    }
    #pragma unroll 8
    for (int k = 0; k < H; k += 4){
      float4 w4 = *(const float4*)(wp + H + k);
      float4 c4 = *(const float4*)(ctxL + k);
      a0 += w4.x * c4.x; a1 += w4.y * c4.y; a2 += w4.z * c4.z; a3 += w4.w * c4.w;
    }
    float o = bp[tid] + (a0 + a1) + (a2 + a3);
    o = fmaxf(o, 0.f);
    outb[(size_t)bt * H + tid] = f2bf(o);
  }
}

// ---------------- Kernel 5: logits = out @ Wfc.T + bfc  (bf16 MFMA) ----------------
// ROUND-10: LDS-staged coalesced epilogue. The old direct store wrote, per
// instruction, 4 x 64B segments (lq -> 4 rows at V-stride) = 1/4 coalescing on
// 131 MB of logits. Now each wave stages its 16x128 slab into padded LDS
// ([64][132]: 2-way write alias = free) and writes row-uniform float2 per lane:
// 64 lanes x 8B = one full 512B transaction per row. Slabs are wave-private ->
// no barrier.
__global__ __launch_bounds__(256, 1) void gemm_kernel(const unsigned short* __restrict__ Ab,
    const unsigned short* __restrict__ Bb, const float* __restrict__ bfc,
    float* __restrict__ Cout){
  int tid = threadIdx.x;
  int l = tid & 63, wv = tid >> 6;
  int lm = l & 15, lq = l >> 4;
  int nBase = blockIdx.x * 128;
  __shared__ __align__(16) float cst[64][132];
  bf16x8 bw[32];
  const unsigned short* bp = Bb + (size_t)(nBase + lm) * H + lq * 8;
  #pragma unroll
  for (int sub = 0; sub < 8; ++sub)
    #pragma unroll
    for (int kk = 0; kk < 4; ++kk)
      bw[sub * 4 + kk] = *(const bf16x8*)(bp + (size_t)sub * 16 * H + kk * 32);
  float bias[8];
  #pragma unroll
  for (int sub = 0; sub < 8; ++sub) bias[sub] = bfc[nBase + lm + sub * 16];
  #pragma unroll 1
  for (int mb = 0; mb < 16; ++mb){
    int rowA = mb * 64 + wv * 16 + lm;
    const unsigned short* ap = Ab + (size_t)rowA * H + lq * 8;
    bf16x8 af[4];
    #pragma unroll
    for (int kk = 0; kk < 4; ++kk) af[kk] = *(const bf16x8*)(ap + kk * 32);
    f32x4 acc[8];
    #pragma unroll
    for (int s = 0; s < 8; ++s) acc[s] = (f32x4){0.f, 0.f, 0.f, 0.f};
    #pragma unroll
    for (int kk = 0; kk < 4; ++kk)
      #pragma unroll
      for (int sub = 0; sub < 8; ++sub)
        acc[sub] = __builtin_amdgcn_mfma_f32_16x16x32_bf16(af[kk], bw[sub * 4 + kk], acc[sub], 0, 0, 0);
    // stage this wave's 16x128 slab (rows wv*16 + lq*4 + r, cols lm + sub*16)
    int lrow = wv * 16 + lq * 4;
    #pragma unroll
    for (int sub = 0; sub < 8; ++sub)
      #pragma unroll
      for (int r = 0; r < 4; ++r)
        cst[lrow + r][lm + sub * 16] = acc[sub][r] + bias[sub];
    // coalesced write: wave wv owns rows wv*16..wv*16+15; 64 lanes x float2 = 512B/row
    int grow0 = mb * 64 + wv * 16;
    #pragma unroll
    for (int rr = 0; rr < 16; ++rr){
      float2 vv = *(const float2*)(&cst[wv * 16 + rr][l * 2]);
      *(float2*)(&Cout[(size_t)(grow0 + rr) * V + nBase + l * 2]) = vv;
    }
  }
}

extern "C" void kernel_launch(void* const* d_in, const int* in_sizes, int n_in,
                              void* d_out, int out_size, void* d_ws, size_t ws_size,
                              hipStream_t stream){
  const int*   x      = (const int*)d_in[0];
  const float* hidden = (const float*)d_in[1];
  const float* table  = (const float*)d_in[2];
  const float* W_ih   = (const float*)d_in[3];
  const float* W_hh   = (const float*)d_in[4];
  const float* b_ih   = (const float*)d_in[5];
  const float* b_hh   = (const float*)d_in[6];
  const float* W1     = (const float*)d_in[7];
  const float* W2     = (const float*)d_in[8];
  const float* v      = (const float*)d_in[9];
  const float* Wp     = (const float*)d_in[10];
  const float* bp     = (const float*)d_in[11];
  const float* Wfc    = (const float*)d_in[12];
  const float* bfc    = (const float*)d_in[13];

  float* out     = (float*)d_out;
  float* logits  = out;                              // (B,T,V)
  float* hid_out = out + (size_t)B * T * V;          // (1,B,H)
  float* w_out   = hid_out + (size_t)B * H;          // (B,T,T)

  float* xp  = (float*)d_ws;
  float* rnn = xp  + (size_t)B * T * H;
  float* q   = rnn + (size_t)B * T * H;
  float* ky  = q   + (size_t)B * T * H;
  unsigned short* outb = (unsigned short*)(ky + (size_t)B * T * H);
  unsigned short* wfcb = outb + (size_t)B * T * H;

  prep_kernel<<<B * T, 128, 0, stream>>>(x, table, W_ih, b_ih, b_hh, xp);
  rnn_kernel<<<B + (V * H) / 4096, 256, 0, stream>>>(xp, hidden, W_hh, Wfc, rnn, hid_out, wfcb);
  qk_kernel<<<B * T, 256, 0, stream>>>(rnn, W1, W2, q, ky);
  attn_kernel<<<B * T, 256, 0, stream>>>(rnn, q, ky, v, Wp, bp, w_out, outb);
  gemm_kernel<<<V / 128, 256, 0, stream>>>(outb, wfcb, bfc, logits);
}